// Round 1
// baseline (1533.058 us; speedup 1.0000x reference)
//
#include <hip/hip_runtime.h>
#include <math.h>

#define NN 50000
#define F 128

// ---------------- degree / norm ----------------
__global__ void deg_init_kernel(float* __restrict__ deg, int n) {
    int i = blockIdx.x * blockDim.x + threadIdx.x;
    if (i < n) deg[i] = 1.0f;  // self-loop
}

__global__ void deg_count_kernel(const int* __restrict__ dst, float* __restrict__ deg, int E) {
    int i = blockIdx.x * blockDim.x + threadIdx.x;
    if (i < E) atomicAdd(&deg[dst[i]], 1.0f);
}

__global__ void dinv_kernel(float* __restrict__ deg, int n) {
    int i = blockIdx.x * blockDim.x + threadIdx.x;
    if (i < n) deg[i] = rsqrtf(deg[i]);  // deg >= 1 always
}

// ---------------- GEMM: h = x @ W ; agg = h * dinv[r]^2 ----------------
// block = 256 threads = 8 row-groups x 32 threads; each thread: 4 rows x 4 cols.
// 32 rows per block.
__global__ __launch_bounds__(256) void gemm_kernel(
    const float* __restrict__ x, const float* __restrict__ W,
    const float* __restrict__ dinv, float* __restrict__ h,
    float* __restrict__ agg, int n) {
    int tid = threadIdx.x;
    int colgrp = tid & 31;        // 0..31
    int rowgrp = tid >> 5;        // 0..7
    int c0 = colgrp * 4;          // 0..124
    int r0 = blockIdx.x * 32 + rowgrp * 4;

    // clamp rows for loads (valid memory), guard stores
    int r[4];
#pragma unroll
    for (int i = 0; i < 4; ++i) r[i] = min(r0 + i, n - 1);

    const float* xr0 = x + (size_t)r[0] * F;
    const float* xr1 = x + (size_t)r[1] * F;
    const float* xr2 = x + (size_t)r[2] * F;
    const float* xr3 = x + (size_t)r[3] * F;
    const float* wp = W + c0;

    float4 a0 = {0, 0, 0, 0}, a1 = {0, 0, 0, 0}, a2 = {0, 0, 0, 0}, a3 = {0, 0, 0, 0};

#pragma unroll 4
    for (int k = 0; k < F; ++k) {
        float4 w = *(const float4*)(wp + (size_t)k * F);
        float x0 = xr0[k], x1 = xr1[k], x2 = xr2[k], x3 = xr3[k];
        a0.x += x0 * w.x; a0.y += x0 * w.y; a0.z += x0 * w.z; a0.w += x0 * w.w;
        a1.x += x1 * w.x; a1.y += x1 * w.y; a1.z += x1 * w.z; a1.w += x1 * w.w;
        a2.x += x2 * w.x; a2.y += x2 * w.y; a2.z += x2 * w.z; a2.w += x2 * w.w;
        a3.x += x3 * w.x; a3.y += x3 * w.y; a3.z += x3 * w.z; a3.w += x3 * w.w;
    }

    float4 acc[4] = {a0, a1, a2, a3};
#pragma unroll
    for (int i = 0; i < 4; ++i) {
        int rr = r0 + i;
        if (rr < n) {
            float di = dinv[rr];
            float s = di * di;
            size_t idx = (size_t)rr * F + c0;
            *(float4*)&h[idx] = acc[i];
            float4 ag;
            ag.x = acc[i].x * s; ag.y = acc[i].y * s;
            ag.z = acc[i].z * s; ag.w = acc[i].w * s;
            *(float4*)&agg[idx] = ag;
        }
    }
}

// ---------------- edge scatter: agg[dst] += h[src] * dinv[src]*dinv[dst] ----------------
// one wave (64 lanes) per edge, 2 floats per lane, grid-stride over edges.
__global__ __launch_bounds__(256) void scatter_kernel(
    const int* __restrict__ src, const int* __restrict__ dst,
    const float* __restrict__ dinv, const float* __restrict__ h,
    float* __restrict__ agg, int E) {
    int lane = threadIdx.x & 63;
    int wid = (blockIdx.x * blockDim.x + threadIdx.x) >> 6;
    int nw = (gridDim.x * blockDim.x) >> 6;
    for (int e = wid; e < E; e += nw) {
        int s = src[e];
        int d = dst[e];
        float nrm = dinv[s] * dinv[d];
        float2 v = *(const float2*)&h[(size_t)s * F + lane * 2];
        float* ap = &agg[(size_t)d * F + lane * 2];
        atomicAdd(ap, v.x * nrm);
        atomicAdd(ap + 1, v.y * nrm);
    }
}

// ---------------- bias (+relu) in-place ----------------
template <bool RELU>
__global__ void bias_kernel(float* __restrict__ a, const float* __restrict__ b, int nvec) {
    int i = blockIdx.x * blockDim.x + threadIdx.x;
    if (i >= nvec) return;
    size_t idx = (size_t)i * 4;
    int c0 = (int)(idx & (F - 1));
    float4 v = *(float4*)&a[idx];
    float4 bb = *(const float4*)&b[c0];
    v.x += bb.x; v.y += bb.y; v.z += bb.z; v.w += bb.w;
    if (RELU) {
        v.x = fmaxf(v.x, 0.0f); v.y = fmaxf(v.y, 0.0f);
        v.z = fmaxf(v.z, 0.0f); v.w = fmaxf(v.w, 0.0f);
    }
    *(float4*)&a[idx] = v;
}

// ---------------- decode: out = sigmoid(dot(z[ls], z[ld])) ----------------
__global__ __launch_bounds__(256) void decode_kernel(
    const int* __restrict__ ls, const int* __restrict__ ld,
    const float* __restrict__ z, float* __restrict__ out, int EL) {
    int lane = threadIdx.x & 63;
    int w = (blockIdx.x * blockDim.x + threadIdx.x) >> 6;
    if (w >= EL) return;
    int a = ls[w];
    int b = ld[w];
    float2 va = *(const float2*)&z[(size_t)a * F + lane * 2];
    float2 vb = *(const float2*)&z[(size_t)b * F + lane * 2];
    float s = va.x * vb.x + va.y * vb.y;
#pragma unroll
    for (int off = 32; off; off >>= 1) s += __shfl_xor(s, off, 64);
    if (lane == 0) out[w] = 1.0f / (1.0f + expf(-s));
}

extern "C" void kernel_launch(void* const* d_in, const int* in_sizes, int n_in,
                              void* d_out, int out_size, void* d_ws, size_t ws_size,
                              hipStream_t stream) {
    const float* x = (const float*)d_in[0];
    const int* ei = (const int*)d_in[1];
    const int* eli = (const int*)d_in[2];
    const float* W1 = (const float*)d_in[3];
    const float* b1 = (const float*)d_in[4];
    const float* W2 = (const float*)d_in[5];
    const float* b2 = (const float*)d_in[6];
    float* out = (float*)d_out;

    int E = in_sizes[1] / 2;
    int EL = in_sizes[2] / 2;
    const int* src = ei;
    const int* dst = ei + E;
    const int* ls = eli;
    const int* ld = eli + EL;
    int n = in_sizes[0] / F;  // 50000

    char* ws = (char*)d_ws;
    float* dinv = (float*)(ws);                          // 50000 f32
    float* h    = (float*)(ws + (1u << 20));             // 25.6 MB
    float* agg1 = (float*)(ws + (1u << 20) + 26214400u); // 25.6 MB (-> z1)
    float* agg2 = (float*)(ws + (1u << 20) + 2u * 26214400u); // 25.6 MB (-> z2)

    const int BS = 256;
    int nb_nodes = (n + BS - 1) / BS;
    int nb_edges = (E + BS - 1) / BS;
    int gemm_blocks = (n + 31) / 32;
    int nvec = n * F / 4;
    int nb_bias = (nvec + BS - 1) / BS;
    int scat_blocks = 4096;
    int dec_blocks = (EL + 3) / 4;

    // degrees / norms
    deg_init_kernel<<<nb_nodes, BS, 0, stream>>>(dinv, n);
    deg_count_kernel<<<nb_edges, BS, 0, stream>>>(dst, dinv, E);
    dinv_kernel<<<nb_nodes, BS, 0, stream>>>(dinv, n);

    // layer 1
    gemm_kernel<<<gemm_blocks, BS, 0, stream>>>(x, W1, dinv, h, agg1, n);
    scatter_kernel<<<scat_blocks, BS, 0, stream>>>(src, dst, dinv, h, agg1, E);
    bias_kernel<true><<<nb_bias, BS, 0, stream>>>(agg1, b1, nvec);

    // layer 2
    gemm_kernel<<<gemm_blocks, BS, 0, stream>>>(agg1, W2, dinv, h, agg2, n);
    scatter_kernel<<<scat_blocks, BS, 0, stream>>>(src, dst, dinv, h, agg2, E);
    bias_kernel<false><<<nb_bias, BS, 0, stream>>>(agg2, b2, nvec);

    // decode
    decode_kernel<<<dec_blocks, BS, 0, stream>>>(ls, ld, agg2, out, EL);
}

// Round 2
// 401.960 us; speedup vs baseline: 3.8140x; 3.8140x over previous
//
#include <hip/hip_runtime.h>
#include <math.h>

#define NN 50000
#define F 128

// ---------------- small utility kernels ----------------
__global__ void zero_int_kernel(int* __restrict__ p, int n) {
    int i = blockIdx.x * blockDim.x + threadIdx.x;
    if (i < n) p[i] = 0;
}

__global__ void copy_int_kernel(const int* __restrict__ a, int* __restrict__ b, int n) {
    int i = blockIdx.x * blockDim.x + threadIdx.x;
    if (i < n) b[i] = a[i];
}

// count in-degree (excl self loop) into cnt
__global__ void deg_count_kernel(const int* __restrict__ dst, int* __restrict__ cnt, int E) {
    int i = blockIdx.x * blockDim.x + threadIdx.x;
    if (i < E) atomicAdd(&cnt[dst[i]], 1);
}

// dinv = rsqrt(cnt + 1)   (self loop adds 1)
__global__ void dinv_kernel(const int* __restrict__ cnt, float* __restrict__ dinv, int n) {
    int i = blockIdx.x * blockDim.x + threadIdx.x;
    if (i < n) dinv[i] = rsqrtf((float)(cnt[i] + 1));
}

// single-block exclusive scan: rowptr[0..n-1] = exscan(cnt), rowptr[n] = total
__global__ __launch_bounds__(1024) void scan_kernel(const int* __restrict__ cnt,
                                                    int* __restrict__ rowptr, int n) {
    __shared__ int wsum[16];
    __shared__ int chunk_total;
    int tid = threadIdx.x;
    int lane = tid & 63;
    int wv = tid >> 6;
    int carry = 0;
    for (int base = 0; base < n; base += 1024) {
        int i = base + tid;
        int val = (i < n) ? cnt[i] : 0;
        int s = val;
#pragma unroll
        for (int off = 1; off < 64; off <<= 1) {
            int t = __shfl_up(s, off, 64);
            if (lane >= off) s += t;
        }
        if (lane == 63) wsum[wv] = s;
        __syncthreads();
        if (wv == 0 && lane < 16) {
            int wval = wsum[lane];
            int ss = wval;
#pragma unroll
            for (int off = 1; off < 16; off <<= 1) {
                int t = __shfl_up(ss, off, 64);
                if (lane >= off) ss += t;
            }
            wsum[lane] = ss - wval;  // exclusive offset for wave
            if (lane == 15) chunk_total = ss;
        }
        __syncthreads();
        int excl = s - val + wsum[wv] + carry;
        if (i < n) rowptr[i] = excl;
        carry += chunk_total;
        __syncthreads();
    }
    if (tid == 0) rowptr[n] = carry;
}

// fill CSR: csr_src[pos] = src[e] bucketed by dst
__global__ void fill_kernel(const int* __restrict__ src, const int* __restrict__ dst,
                            int* __restrict__ cursor, int* __restrict__ csr_src, int E) {
    int i = blockIdx.x * blockDim.x + threadIdx.x;
    if (i < E) {
        int d = dst[i];
        int pos = atomicAdd(&cursor[d], 1);
        csr_src[pos] = src[i];
    }
}

// ---------------- GEMM: g = (x @ W) * dinv[row] ----------------
__global__ __launch_bounds__(256) void gemm_kernel(
    const float* __restrict__ x, const float* __restrict__ W,
    const float* __restrict__ dinv, float* __restrict__ g, int n) {
    int tid = threadIdx.x;
    int colgrp = tid & 31;
    int rowgrp = tid >> 5;
    int c0 = colgrp * 4;
    int r0 = blockIdx.x * 32 + rowgrp * 4;

    int r[4];
#pragma unroll
    for (int i = 0; i < 4; ++i) r[i] = min(r0 + i, n - 1);

    const float* xr0 = x + (size_t)r[0] * F;
    const float* xr1 = x + (size_t)r[1] * F;
    const float* xr2 = x + (size_t)r[2] * F;
    const float* xr3 = x + (size_t)r[3] * F;
    const float* wp = W + c0;

    float4 a0 = {0, 0, 0, 0}, a1 = {0, 0, 0, 0}, a2 = {0, 0, 0, 0}, a3 = {0, 0, 0, 0};

#pragma unroll 4
    for (int k = 0; k < F; ++k) {
        float4 w = *(const float4*)(wp + (size_t)k * F);
        float x0 = xr0[k], x1 = xr1[k], x2 = xr2[k], x3 = xr3[k];
        a0.x += x0 * w.x; a0.y += x0 * w.y; a0.z += x0 * w.z; a0.w += x0 * w.w;
        a1.x += x1 * w.x; a1.y += x1 * w.y; a1.z += x1 * w.z; a1.w += x1 * w.w;
        a2.x += x2 * w.x; a2.y += x2 * w.y; a2.z += x2 * w.z; a2.w += x2 * w.w;
        a3.x += x3 * w.x; a3.y += x3 * w.y; a3.z += x3 * w.z; a3.w += x3 * w.w;
    }

    float4 acc[4] = {a0, a1, a2, a3};
#pragma unroll
    for (int i = 0; i < 4; ++i) {
        int rr = r0 + i;
        if (rr < n) {
            float di = dinv[rr];
            size_t idx = (size_t)rr * F + c0;
            float4 gg;
            gg.x = acc[i].x * di; gg.y = acc[i].y * di;
            gg.z = acc[i].z * di; gg.w = acc[i].w * di;
            *(float4*)&g[idx] = gg;
        }
    }
}

// ---------------- aggregate: out[d] = [relu](dinv[d]*(sum_{s in N(d)} g[s] + g[d]) + b) ----------------
// one wave per dst node, 2 floats per lane
template <bool RELU>
__global__ __launch_bounds__(256) void aggregate_kernel(
    const int* __restrict__ rowptr, const int* __restrict__ csr_src,
    const float* __restrict__ dinv, const float* __restrict__ g,
    const float* __restrict__ bias, float* __restrict__ out, int n) {
    int lane = threadIdx.x & 63;
    int d = (blockIdx.x * blockDim.x + threadIdx.x) >> 6;
    if (d >= n) return;
    int c = lane * 2;

    // self-loop term
    float2 acc = *(const float2*)&g[(size_t)d * F + c];

    int e = rowptr[d];
    int end = rowptr[d + 1];
    for (; e + 4 <= end; e += 4) {
        int s0 = csr_src[e];
        int s1 = csr_src[e + 1];
        int s2 = csr_src[e + 2];
        int s3 = csr_src[e + 3];
        float2 v0 = *(const float2*)&g[(size_t)s0 * F + c];
        float2 v1 = *(const float2*)&g[(size_t)s1 * F + c];
        float2 v2 = *(const float2*)&g[(size_t)s2 * F + c];
        float2 v3 = *(const float2*)&g[(size_t)s3 * F + c];
        acc.x += v0.x + v1.x + v2.x + v3.x;
        acc.y += v0.y + v1.y + v2.y + v3.y;
    }
    for (; e < end; ++e) {
        int s = csr_src[e];
        float2 v = *(const float2*)&g[(size_t)s * F + c];
        acc.x += v.x;
        acc.y += v.y;
    }

    float di = dinv[d];
    float2 b = *(const float2*)&bias[c];
    float2 r;
    r.x = di * acc.x + b.x;
    r.y = di * acc.y + b.y;
    if (RELU) {
        r.x = fmaxf(r.x, 0.0f);
        r.y = fmaxf(r.y, 0.0f);
    }
    *(float2*)&out[(size_t)d * F + c] = r;
}

// ---------------- decode: out = sigmoid(dot(z[ls], z[ld])) ----------------
__global__ __launch_bounds__(256) void decode_kernel(
    const int* __restrict__ ls, const int* __restrict__ ld,
    const float* __restrict__ z, float* __restrict__ out, int EL) {
    int lane = threadIdx.x & 63;
    int w = (blockIdx.x * blockDim.x + threadIdx.x) >> 6;
    if (w >= EL) return;
    int a = ls[w];
    int b = ld[w];
    float2 va = *(const float2*)&z[(size_t)a * F + lane * 2];
    float2 vb = *(const float2*)&z[(size_t)b * F + lane * 2];
    float s = va.x * vb.x + va.y * vb.y;
#pragma unroll
    for (int off = 32; off; off >>= 1) s += __shfl_xor(s, off, 64);
    if (lane == 0) out[w] = 1.0f / (1.0f + expf(-s));
}

extern "C" void kernel_launch(void* const* d_in, const int* in_sizes, int n_in,
                              void* d_out, int out_size, void* d_ws, size_t ws_size,
                              hipStream_t stream) {
    const float* x = (const float*)d_in[0];
    const int* ei = (const int*)d_in[1];
    const int* eli = (const int*)d_in[2];
    const float* W1 = (const float*)d_in[3];
    const float* b1 = (const float*)d_in[4];
    const float* W2 = (const float*)d_in[5];
    const float* b2 = (const float*)d_in[6];
    float* out = (float*)d_out;

    int E = in_sizes[1] / 2;
    int EL = in_sizes[2] / 2;
    const int* src = ei;
    const int* dst = ei + E;
    const int* ls = eli;
    const int* ld = eli + EL;
    int n = in_sizes[0] / F;  // 50000

    char* ws = (char*)d_ws;
    float* dinv   = (float*)(ws);                 // [0, 1MB): n floats
    int*   rowptr = (int*)(ws + (1u << 20));      // [1MB, 2MB): n+1 ints
    int*   cursor = (int*)(ws + (2u << 20));      // [2MB, 3MB): n ints (also cnt)
    int*   csr    = (int*)(ws + (3u << 20));      // [3MB, 8MB): E ints (3.2MB)
    float* bufA   = (float*)(ws + (8u << 20));    // [8MB, 33.6MB): g
    float* bufB   = (float*)(ws + (8u << 20) + 26214400u);  // [34MB,...): z1 / z2

    const int BS = 256;
    int nb_nodes = (n + BS - 1) / BS;
    int nb_edges = (E + BS - 1) / BS;
    int gemm_blocks = (n + 31) / 32;
    int agg_blocks = (n + 3) / 4;   // 4 waves/block, 1 wave/node
    int dec_blocks = (EL + 3) / 4;

    // ---- CSR build (once, reused for both layers) ----
    zero_int_kernel<<<nb_nodes, BS, 0, stream>>>(cursor, n);
    deg_count_kernel<<<nb_edges, BS, 0, stream>>>(dst, cursor, E);
    dinv_kernel<<<nb_nodes, BS, 0, stream>>>(cursor, dinv, n);
    scan_kernel<<<1, 1024, 0, stream>>>(cursor, rowptr, n);
    copy_int_kernel<<<nb_nodes, BS, 0, stream>>>(rowptr, cursor, n);
    fill_kernel<<<nb_edges, BS, 0, stream>>>(src, dst, cursor, csr, E);

    // ---- layer 1: g = (x@W1)*dinv ; z1 = relu(dinv*(sum g + g) + b1) ----
    gemm_kernel<<<gemm_blocks, BS, 0, stream>>>(x, W1, dinv, bufA, n);
    aggregate_kernel<true><<<agg_blocks, BS, 0, stream>>>(rowptr, csr, dinv, bufA, b1, bufB, n);

    // ---- layer 2: g = (z1@W2)*dinv ; z2 = dinv*(sum g + g) + b2 ----
    gemm_kernel<<<gemm_blocks, BS, 0, stream>>>(bufB, W2, dinv, bufA, n);
    aggregate_kernel<false><<<agg_blocks, BS, 0, stream>>>(rowptr, csr, dinv, bufA, b2, bufB, n);

    // ---- decode ----
    decode_kernel<<<dec_blocks, BS, 0, stream>>>(ls, ld, bufB, out, EL);
}